// Round 1
// baseline (1641.886 us; speedup 1.0000x reference)
//
#include <hip/hip_runtime.h>
#include <math.h>

#define N_TOKENS 262144
#define HID      1024
#define NEXP     64
#define TOPK     2
#define CAPACITY 10240   // int(262144*2/64*1.25)

// d_out element offsets (fp32)
#define OUT_IDX  0
#define OUT_W    (N_TOKENS*TOPK)        // 524288
#define OUT_MASK (2*N_TOKENS*TOPK)      // 1048576
#define OUT_CNT  (3*N_TOKENS*TOPK)      // 1572864
#define OUT_DROP (OUT_CNT + NEXP)       // 1572928

// ---------------- Kernel A: gate GEMM (fp32 vector) + top-2 + pre-mask weights ----------
// block = 128 threads, tile = 128 tokens x 64 experts, per-thread 8x8, KC=32 k-chunk.
#define BM 128
#define KC 32

__launch_bounds__(128, 2)
__global__ void gate_topk_kernel(const float* __restrict__ x,
                                 const float* __restrict__ W,
                                 float* __restrict__ out)
{
    __shared__ float xs[KC][BM];    // k-major x tile, 16 KB
    __shared__ float wsh[KC][NEXP]; // k-major W tile, 8 KB

    const int tid = threadIdx.x;
    const int ty  = tid >> 3;   // 0..15 -> token groups of 8
    const int tx  = tid & 7;    // 0..7  -> expert groups of 8
    const int tb  = blockIdx.x * BM;

    const float* xrow = x + (size_t)(tb + tid) * HID;

    float acc[8][8];
#pragma unroll
    for (int i = 0; i < 8; i++)
#pragma unroll
        for (int j = 0; j < 8; j++) acc[i][j] = 0.0f;

    for (int k0 = 0; k0 < HID; k0 += KC) {
        __syncthreads();   // protect LDS reuse from previous chunk's readers
        // stage x: thread owns token row `tid`, 32 contiguous k as 8 float4, transpose to k-major
#pragma unroll
        for (int q = 0; q < 8; q++) {
            float4 v = *reinterpret_cast<const float4*>(xrow + k0 + q * 4);
            xs[q * 4 + 0][tid] = v.x;
            xs[q * 4 + 1][tid] = v.y;
            xs[q * 4 + 2][tid] = v.z;
            xs[q * 4 + 3][tid] = v.w;
        }
        // stage W chunk: 32x64 floats = 512 float4, coalesced, layout matches global
#pragma unroll
        for (int q = 0; q < 4; q++) {
            int p = q * 128 + tid;  // float4 index 0..511
            float4 v = *reinterpret_cast<const float4*>(W + (size_t)k0 * NEXP + p * 4);
            *reinterpret_cast<float4*>(&wsh[0][0] + p * 4) = v;
        }
        __syncthreads();

        // chunk accumulator (reduces fp32 accumulation error vs one long chain)
        float cacc[8][8];
#pragma unroll
        for (int i = 0; i < 8; i++)
#pragma unroll
            for (int j = 0; j < 8; j++) cacc[i][j] = 0.0f;

#pragma unroll
        for (int kk = 0; kk < KC; kk++) {
            float4 a0 = *reinterpret_cast<const float4*>(&xs[kk][ty * 8]);
            float4 a1 = *reinterpret_cast<const float4*>(&xs[kk][ty * 8 + 4]);
            float4 b0 = *reinterpret_cast<const float4*>(&wsh[kk][tx * 8]);
            float4 b1 = *reinterpret_cast<const float4*>(&wsh[kk][tx * 8 + 4]);
            float a[8] = {a0.x, a0.y, a0.z, a0.w, a1.x, a1.y, a1.z, a1.w};
            float b[8] = {b0.x, b0.y, b0.z, b0.w, b1.x, b1.y, b1.z, b1.w};
#pragma unroll
            for (int i = 0; i < 8; i++)
#pragma unroll
                for (int j = 0; j < 8; j++)
                    cacc[i][j] = fmaf(a[i], b[j], cacc[i][j]);
        }
#pragma unroll
        for (int i = 0; i < 8; i++)
#pragma unroll
            for (int j = 0; j < 8; j++) acc[i][j] += cacc[i][j];
    }

    // top-2 per token row: local scan over this thread's 8 experts (ascending index),
    // then 3 xor-shuffle merge rounds across the 8 tx lanes (expert-index order,
    // tie-break = lower index, matching jax.lax.top_k).
    float r_v1 = 0.f, r_v2 = 0.f;
    int   r_i1 = 0,   r_i2 = 0;
#pragma unroll
    for (int i = 0; i < 8; i++) {
        float v1 = -INFINITY, v2 = -INFINITY;
        int   i1 = 0,         i2 = 0;
#pragma unroll
        for (int j = 0; j < 8; j++) {
            float v = acc[i][j];
            int idx = tx * 8 + j;
            if (v > v1)      { v2 = v1; i2 = i1; v1 = v; i1 = idx; }
            else if (v > v2) { v2 = v;  i2 = idx; }
        }
#pragma unroll
        for (int m = 1; m < 8; m <<= 1) {
            float pv1 = __shfl_xor(v1, m, 64);
            int   pi1 = __shfl_xor(i1, m, 64);
            float pv2 = __shfl_xor(v2, m, 64);
            int   pi2 = __shfl_xor(i2, m, 64);
            bool afirst = (v1 > pv1) || (v1 == pv1 && i1 < pi1);
            if (afirst) {
                bool second = (v2 > pv1) || (v2 == pv1 && i2 < pi1);
                if (!second) { v2 = pv1; i2 = pi1; }
            } else {
                bool second = (v1 > pv2) || (v1 == pv2 && i1 < pi2);
                if (second) { v2 = v1; i2 = i1; }
                else        { v2 = pv2; i2 = pi2; }
                v1 = pv1; i1 = pi1;
            }
        }
        if (i == tx) { r_v1 = v1; r_v2 = v2; r_i1 = i1; r_i2 = i2; }
    }

    // weights: softmax denominators cancel -> w1 = 1/(1+exp(l2-l1)), w2 = 1-w1 form
    const int token = tb + ty * 8 + tx;
    float e2 = expf(r_v2 - r_v1);
    float s  = 1.0f / (1.0f + e2);
    float w1 = s, w2 = e2 * s;

    reinterpret_cast<float2*>(out + OUT_IDX)[token] = make_float2((float)r_i1, (float)r_i2);
    reinterpret_cast<float2*>(out + OUT_W)[token]   = make_float2(w1, w2);
}

// ---------------- Kernel B: per-chunk expert histograms (chunk = 2048 assignments) ----
__launch_bounds__(256)
__global__ void hist_kernel(const float* __restrict__ out, int* __restrict__ bh)
{
    __shared__ int h[NEXP];
    const int tid = threadIdx.x, b = blockIdx.x;
    if (tid < NEXP) h[tid] = 0;
    __syncthreads();
    const float* idxf = out + OUT_IDX + (size_t)b * 2048;
#pragma unroll
    for (int i = 0; i < 8; i++) {
        int e = (int)idxf[i * 256 + tid];
        atomicAdd(&h[e], 1);
    }
    __syncthreads();
    if (tid < NEXP) bh[b * NEXP + tid] = h[tid];
}

// ---------------- Kernel C: exclusive scan over 256 chunks per expert + stats --------
__launch_bounds__(256)
__global__ void scan_kernel(int* __restrict__ bh, float* __restrict__ out)
{
    const int tid = threadIdx.x;
    const int e = tid & 63, seg = tid >> 6;   // 4 segments x 64 chunks
    __shared__ int segsum[4][NEXP];
    int sum = 0;
    for (int b = seg * 64; b < seg * 64 + 64; b++) sum += bh[b * NEXP + e];
    segsum[seg][e] = sum;
    __syncthreads();
    int base = 0;
    for (int s = 0; s < seg; s++) base += segsum[s][e];
    int tot = segsum[0][e] + segsum[1][e] + segsum[2][e] + segsum[3][e];
    int run = base;
    for (int b = seg * 64; b < seg * 64 + 64; b++) {
        int c = bh[b * NEXP + e];
        bh[b * NEXP + e] = run;   // exclusive base for chunk b, expert e
        run += c;
    }
    if (seg == 0) {
        out[OUT_CNT + e] = (float)(tot < CAPACITY ? tot : CAPACITY);
        int over = tot - CAPACITY; if (over < 0) over = 0;
        for (int off = 32; off > 0; off >>= 1) over += __shfl_down(over, off);
        if (e == 0) out[OUT_DROP] = (float)over;
    }
}

// ---------------- Kernel D: rank-within-expert -> capacity mask + final weights ------
// block = 64 threads, chunk = 2048 assignments (1024 tokens); thread walks 32 in order.
__launch_bounds__(64)
__global__ void mask_kernel(float* __restrict__ out, const int* __restrict__ bh)
{
    __shared__ int th[64 * NEXP];   // per-thread running counters, 16 KB
    const int tid = threadIdx.x, b = blockIdx.x;
#pragma unroll
    for (int e = 0; e < NEXP; e++) th[tid * NEXP + e] = 0;
    __syncthreads();

    const float* idxf = out + OUT_IDX;
    const int a_base = b * 2048 + tid * 32;
    for (int j = 0; j < 32; j++) {
        int e = (int)idxf[a_base + j];
        th[tid * NEXP + e]++;
    }
    __syncthreads();
    // exclusive scan across the 64 thread-rows for expert `tid`, seeded by chunk base
    {
        int run = bh[b * NEXP + tid];
        for (int t = 0; t < 64; t++) {
            int c = th[t * NEXP + tid];
            th[t * NEXP + tid] = run;
            run += c;
        }
    }
    __syncthreads();

    float* wf = out + OUT_W;
    float* mf = out + OUT_MASK;
    const int t0 = b * 1024 + tid * 16;
    for (int m = 0; m < 16; m++) {
        int tok = t0 + m;
        int a0 = 2 * tok;
        int e0 = (int)idxf[a0];
        int e1 = (int)idxf[a0 + 1];
        int p0 = th[tid * NEXP + e0]++;
        int p1 = th[tid * NEXP + e1]++;
        float f0 = (p0 < CAPACITY) ? 1.0f : 0.0f;
        float f1 = (p1 < CAPACITY) ? 1.0f : 0.0f;
        float inv = 1.0f / ((f0 + f1) + 1e-10f);
        float w0 = wf[a0]     * f0 * inv;
        float w1 = wf[a0 + 1] * f1 * inv;
        reinterpret_cast<float2*>(wf)[tok] = make_float2(w0, w1);
        reinterpret_cast<float2*>(mf)[tok] = make_float2(f0, f1);
    }
}

extern "C" void kernel_launch(void* const* d_in, const int* in_sizes, int n_in,
                              void* d_out, int out_size, void* d_ws, size_t ws_size,
                              hipStream_t stream) {
    const float* x = (const float*)d_in[0];   // [262144, 1024] fp32
    const float* W = (const float*)d_in[1];   // [1024, 64] fp32
    float* out = (float*)d_out;
    int* bh = (int*)d_ws;                     // 256*64 ints = 64 KB

    gate_topk_kernel<<<N_TOKENS / BM, 128, 0, stream>>>(x, W, out);
    hist_kernel<<<(N_TOKENS * TOPK) / 2048, 256, 0, stream>>>(out, bh);
    scan_kernel<<<1, 256, 0, stream>>>(bh, out);
    mask_kernel<<<(N_TOKENS * TOPK) / 2048, 64, 0, stream>>>(out, bh);
}